// Round 1
// baseline (43.656 us; speedup 1.0000x reference)
//
#include <hip/hip_runtime.h>

#define NDENSE 13
#define NSPARSE 26
#define FIELD_NUM 39
#define KDIM 16
#define ROW_F4 156   // 39*16/4 float4 per v row
#define BATCH 4096

__global__ __launch_bounds__(256) void ffm_kernel(
    const float* __restrict__ dense,    // [B,13]
    const int*   __restrict__ sparse,   // [B,26]
    const float* __restrict__ w0,       // [1]
    const float* __restrict__ w,        // [26013]
    const float4* __restrict__ v4,      // [26013 * 156] float4 view of v
    float* __restrict__ out)            // [B]
{
    const int wave = threadIdx.x >> 6;
    const int lane = threadIdx.x & 63;
    const int b = blockIdx.x * 4 + wave;

    // Per-lane copy of the 13 dense values for this row (wave-uniform addresses,
    // HW broadcasts; unrolled so dv[] stays in registers).
    float dv[NDENSE];
#pragma unroll
    for (int d = 0; d < NDENSE; ++d) dv[d] = dense[b * NDENSE + d];

    // Lane j < 26 owns gather index j: global feature id = sparse + 13 + 1000*j
    int myidx = 0;
    if (lane < NSPARSE) {
        myidx = sparse[b * NSPARSE + lane] + NDENSE + 1000 * lane;
    }

    float4 s = make_float4(0.f, 0.f, 0.f, 0.f);  // per-lane k-group partial of sum_f field_f
    float  sq = 0.f;                             // partial of sum_{f,k} field_f^2

#pragma unroll
    for (int p = 0; p < 3; ++p) {
        const int e4 = lane + 64 * p;            // float4 element index within the 624-float row
        if (e4 < ROW_F4) {
            float4 acc = make_float4(0.f, 0.f, 0.f, 0.f);
            // dense contribution: sum_d dense[d] * v[d][e]  (v[:13] is L2-hot, shared by all rows)
#pragma unroll
            for (int d = 0; d < NDENSE; ++d) {
                const float4 vv = v4[d * ROW_F4 + e4];
                acc.x += dv[d] * vv.x; acc.y += dv[d] * vv.y;
                acc.z += dv[d] * vv.z; acc.w += dv[d] * vv.w;
            }
            // sparse gathers: 26 contiguous 2496B rows, coalesced float4 reads
#pragma unroll
            for (int j = 0; j < NSPARSE; ++j) {
                const int ij = __shfl(myidx, j);
                const float4 vv = v4[ij * ROW_F4 + e4];
                acc.x += vv.x; acc.y += vv.y; acc.z += vv.z; acc.w += vv.w;
            }
            // e4 & 3 == lane & 3 for all passes -> lane's k-group is fixed
            s.x += acc.x; s.y += acc.y; s.z += acc.z; s.w += acc.w;
            sq  += acc.x * acc.x + acc.y * acc.y + acc.z * acc.z + acc.w * acc.w;
        }
    }

    // Reduce s over the 16 lanes sharing the same k-group (lane & 3 preserved by these masks)
#pragma unroll
    for (int m = 4; m <= 32; m <<= 1) {
        s.x += __shfl_xor(s.x, m);
        s.y += __shfl_xor(s.y, m);
        s.z += __shfl_xor(s.z, m);
        s.w += __shfl_xor(s.w, m);
    }
    float s2 = s.x * s.x + s.y * s.y + s.z * s.z + s.w * s.w;  // ||s_{k-group}||^2
    s2 += __shfl_xor(s2, 1);   // combine the 4 k-groups
    s2 += __shfl_xor(s2, 2);

    // Full-wave reduce of sumsq
#pragma unroll
    for (int m = 1; m <= 32; m <<= 1) sq += __shfl_xor(sq, m);

    // First order: w0 + dense @ w[:13] + sum_j w[idx_j]
    float fo = 0.f;
    if (lane < NSPARSE) fo = w[myidx];
    if (lane < NDENSE)  fo += dense[b * NDENSE + lane] * w[lane];
#pragma unroll
    for (int m = 1; m <= 32; m <<= 1) fo += __shfl_xor(fo, m);

    if (lane == 0) {
        out[b] = w0[0] + fo + 0.5f * (s2 - sq);
    }
}

extern "C" void kernel_launch(void* const* d_in, const int* in_sizes, int n_in,
                              void* d_out, int out_size, void* d_ws, size_t ws_size,
                              hipStream_t stream) {
    const float*  dense  = (const float*)d_in[0];
    const int*    sparse = (const int*)d_in[1];
    const float*  w0     = (const float*)d_in[2];
    const float*  w      = (const float*)d_in[3];
    const float4* v4     = (const float4*)d_in[4];
    float* out = (float*)d_out;

    dim3 grid(BATCH / 4);   // 4 rows (waves) per 256-thread block
    dim3 block(256);
    hipLaunchKernelGGL(ffm_kernel, grid, block, 0, stream,
                       dense, sparse, w0, w, v4, out);
}